// Round 24
// baseline (32.246 us; speedup 1.0000x reference)
//
#include <hip/hip_runtime.h>
#include <math.h>

// Problem constants
#define BB 8
#define CC 3
#define DD 24
#define HH 128
#define WW 128
#define HW (HH * WW)
#define OCC 16
#define HOUT 126
#define WOUT 126

typedef short bf16x8 __attribute__((ext_vector_type(8)));   // 4 VGPR
typedef float f32x4 __attribute__((ext_vector_type(4)));
typedef unsigned int u32;
typedef u32 u32x4 __attribute__((ext_vector_type(4)));
typedef const __attribute__((address_space(1))) u32 ag_u32;  // global
typedef __attribute__((address_space(3))) u32 as_u32;        // LDS

#define MFMA(a, b, c) __builtin_amdgcn_mfma_f32_16x16x32_bf16((a), (b), (c), 0, 0, 0)
// (a>>16) | (c & 0xffff0000) == v_perm_b32(hi=c, lo=a, 0x07060302)
#define PKHI(a, c) __builtin_amdgcn_perm((c), (a), 0x07060302u)

// ROUND 24: r23 + compile-time memory fences. r23's absmax 5.7e-2 (15x the
// expected 3.9e-3) is consistent with the compiler hoisting a next-step
// STAGE (DMA write to buf (dz+2)%3) above the current step's ds_reads of
// the SAME buffer (and prologue STAGE(3,0) above RDPK(0) of buf0) — the
// only unfenced seam in the schedule; the buffer/step algebra itself
// verifies. FENCE = IR-level memory barrier (empty asm, 0 instructions) +
// sched_barrier(0) (MIR scheduler) pins program order at each seam.
#define FENCE                                                                 \
  do {                                                                        \
    asm volatile("" ::: "memory");                                            \
    __builtin_amdgcn_sched_barrier(0);                                        \
  } while (0)

#define STAGE(P, BK)                                                          \
  do {                                                                        \
    const float* _gp = xb + (size_t)(P)*HW;                                   \
    __builtin_amdgcn_global_load_lds((ag_u32*)(_gp + srcoff[0]),              \
                                     (as_u32*)(myt + (BK)*192 + 0), 4, 0, 0); \
    __builtin_amdgcn_global_load_lds((ag_u32*)(_gp + srcoff[1]),              \
                                     (as_u32*)(myt + (BK)*192 + 64), 4, 0, 0);\
    __builtin_amdgcn_global_load_lds((ag_u32*)(_gp + srcoff[2]),              \
                                     (as_u32*)(myt + (BK)*192 + 128), 4, 0, 0);\
  } while (0)

#define RDPK(BK, FH)                                                          \
  do {                                                                        \
    u32 _u[8];                                                                \
    _Pragma("unroll") for (int _j = 0; _j < 8; ++_j)                          \
        _u[_j] = __float_as_uint(myt[(BK)*192 + ldsoff[_j]]);                 \
    pack_hi(_u, FH);                                                          \
  } while (0)

__device__ __forceinline__ void pack_hi(const u32 (&u)[8], bf16x8& fh) {
  u32x4 hd;
#pragma unroll
  for (int p = 0; p < 4; ++p) hd[p] = PKHI(u[2 * p], u[2 * p + 1]);
  fh = __builtin_bit_cast(bf16x8, hd);
}

#define STEPF(P4, BS, BR, WAITS, FA, FB, FC)                                  \
  do {                                                                        \
    FENCE;            /* pin prior ds_reads before this DMA write */          \
    STAGE(P4, BS);                                                            \
    asm volatile(WAITS ::: "memory");                                         \
    __builtin_amdgcn_sched_barrier(0);                                        \
    RDPK(BR, FC);                                                             \
    f32x4 acc = MFMA(wa[0], FA, z4);                                          \
    acc = MFMA(wa[1], FB, acc);                                               \
    acc = MFMA(wa[2], FC, acc);                                               \
    mn.x = fminf(mn.x, acc.x); mn.y = fminf(mn.y, acc.y);                     \
    mn.z = fminf(mn.z, acc.z); mn.w = fminf(mn.w, acc.w);                     \
  } while (0)

#define STEPN(BR, WAITS, FA, FB, FC)                                          \
  do {                                                                        \
    FENCE;                                                                    \
    asm volatile(WAITS ::: "memory");                                         \
    __builtin_amdgcn_sched_barrier(0);                                        \
    RDPK(BR, FC);                                                             \
    f32x4 acc = MFMA(wa[0], FA, z4);                                          \
    acc = MFMA(wa[1], FB, acc);                                               \
    acc = MFMA(wa[2], FC, acc);                                               \
    mn.x = fminf(mn.x, acc.x); mn.y = fminf(mn.y, acc.y);                     \
    mn.z = fminf(mn.z, acc.z); mn.w = fminf(mn.w, acc.w);                     \
  } while (0)

__global__ __launch_bounds__(256) void conv_min_softmax_mfma(
    const float* __restrict__ x, const float* __restrict__ wt,
    float* __restrict__ out) {
  __shared__ float tile[4][3][192];  // [wave][buf][slot], 9216 B/block

  const int tid = threadIdx.x;
  const int lane = tid & 63;
  const int wv = tid >> 6;            // wave id 0..3
  const int q15 = lane & 15;          // pixel (B col) and oc (A row)
  const int g = lane >> 4;            // kw (g<3) / row-8+pad group (g=3)
  const int b = blockIdx.x;
  const int h = blockIdx.y;
  const int wti = blockIdx.z * 4 + wv;
  const int w0 = (wti == 7) ? 110 : wti * 16;  // overlap last tile (no OOB)

  float* myt = &tile[wv][0][0];

  // Stage source offsets: linear slot i = ld*64+lane -> (row=i/19, col=i%19)
  // row=(c,kh)=(row/3,row%3); col 18 never read -> clamp to 17. i>=171: 0.
  int srcoff[3];
#pragma unroll
  for (int ld = 0; ld < 3; ++ld) {
    const int i = ld * 64 + lane;
    if (i < 171) {
      const int row = i / 19;
      int col = i % 19;
      if (col == 18) col = 17;
      srcoff[ld] = (row / 3) * DD * HW + (row % 3) * WW + w0 + col;
    } else {
      srcoff[ld] = 0;
    }
  }

  // ds_read slot offsets (elements): g<3 -> row j, col q15+g;
  // g=3 -> j<3: row 8, col q15+j; pads reuse row-8 base (A-side weight 0).
  int ldsoff[8];
#pragma unroll
  for (int j = 0; j < 8; ++j) {
    ldsoff[j] = (g < 3) ? (j * 19 + q15 + g)
                        : (8 * 19 + q15 + ((j < 3) ? j : 0));
  }

  // Weight fragments (A), per kd-tile t: single-term RTN bf16, same slot
  // bijection as B; pads (g=3, j>=3) = 0.  (r22-verbatim)
  bf16x8 wa[3];
#pragma unroll
  for (int t = 0; t < 3; ++t) {
    u32 u[8];
#pragma unroll
    for (int j = 0; j < 8; ++j) {
      float v = 0.f;
      if (g < 3) {
        v = wt[q15 * 81 + (j / 3) * 27 + t * 9 + (j % 3) * 3 + g];
      } else if (j < 3) {
        v = wt[q15 * 81 + 2 * 27 + t * 9 + 2 * 3 + j];
      }
      const u32 ub = __float_as_uint(v);
      u[j] = ub + 0x7fffu + ((ub >> 16) & 1u);  // round-to-nearest-even bf16
    }
    u32x4 hd;
#pragma unroll
    for (int p = 0; p < 4; ++p) hd[p] = PKHI(u[2 * p], u[2 * p + 1]);
    wa[t] = __builtin_bit_cast(bf16x8, hd);
  }

  const float* xb = x + ((size_t)b * CC * DD) * HW + (size_t)h * WW;

  const f32x4 z4 = {0.f, 0.f, 0.f, 0.f};
  f32x4 mn = {INFINITY, INFINITY, INFINITY, INFINITY};
  bf16x8 f0, f1, f2;

  // Prologue: stage planes 0,1; drain; pack f0,f1; FENCE (RDPK(0) reads
  // buf0, STAGE(3,0) rewrites buf0 — must not reorder); stage planes 2,3.
  STAGE(0, 0);
  STAGE(1, 1);
  asm volatile("s_waitcnt vmcnt(0)" ::: "memory");
  __builtin_amdgcn_sched_barrier(0);
  RDPK(0, f0);
  RDPK(1, f1);
  FENCE;
  STAGE(2, 2);
  STAGE(3, 0);

  // Steps dz=0..17: stage plane dz+4 -> buf[(dz+4)%3]; vmcnt(6) retires
  // stage(dz+2); read plane dz+2 from buf[(dz+2)%3]; 3 MFMAs; min.
#pragma clang loop unroll(disable)
  for (int dzb = 0; dzb < 18; dzb += 3) {
    STEPF(dzb + 4, 1, 2, "s_waitcnt vmcnt(6)", f0, f1, f2);
    STEPF(dzb + 5, 2, 0, "s_waitcnt vmcnt(6)", f1, f2, f0);
    STEPF(dzb + 6, 0, 1, "s_waitcnt vmcnt(6)", f2, f0, f1);
  }
  // Tail dz=18..21 (planes 22,23 staged at dz=18,19; then drain 3 -> 0).
  STEPF(22, 1, 2, "s_waitcnt vmcnt(6)", f0, f1, f2);
  STEPF(23, 2, 0, "s_waitcnt vmcnt(6)", f1, f2, f0);
  STEPN(1, "s_waitcnt vmcnt(3)", f2, f0, f1);
  STEPN(2, "s_waitcnt vmcnt(0)", f0, f1, f2);

  // Softmax over oc for this lane's pixel: 4 in-lane regs (oc = g*4+r) +
  // lanes sharing q15 across g (xor 16, 32).
  float mx = fmaxf(fmaxf(mn.x, mn.y), fmaxf(mn.z, mn.w));
  mx = fmaxf(mx, __shfl_xor(mx, 16));
  mx = fmaxf(mx, __shfl_xor(mx, 32));
  const float e0 = __expf(mn.x - mx);
  const float e1 = __expf(mn.y - mx);
  const float e2 = __expf(mn.z - mx);
  const float e3 = __expf(mn.w - mx);
  float s = (e0 + e1) + (e2 + e3);
  s += __shfl_xor(s, 16);
  s += __shfl_xor(s, 32);
  const float inv = 1.f / s;

  // Store: out[b][oc = g*4+r][h][w0+q15]; 16 consecutive pixels per (g,r).
  float* ob = out + (((size_t)(b * OCC + g * 4) * HOUT + h) * WOUT) + w0 + q15;
  const size_t os = (size_t)HOUT * WOUT;
  ob[0 * os] = e0 * inv;
  ob[1 * os] = e1 * inv;
  ob[2 * os] = e2 * inv;
  ob[3 * os] = e3 * inv;
}

extern "C" void kernel_launch(void* const* d_in, const int* in_sizes, int n_in,
                              void* d_out, int out_size, void* d_ws, size_t ws_size,
                              hipStream_t stream) {
  const float* x = (const float*)d_in[0];
  const float* wt = (const float*)d_in[1];
  float* out = (float*)d_out;

  dim3 grid(BB, HOUT, 2);   // b (XCD-pinned), h, w-tile-pair
  dim3 block(256, 1, 1);    // 4 waves = 4 w-tiles
  conv_min_softmax_mfma<<<grid, block, 0, stream>>>(x, wt, out);
}

// Round 25
// 25.084 us; speedup vs baseline: 1.2855x; 1.2855x over previous
//
#include <hip/hip_runtime.h>
#include <math.h>

// Problem constants
#define BB 8
#define CC 3
#define DD 24
#define HH 128
#define WW 128
#define HW (HH * WW)
#define OCC 16
#define HOUT 126
#define WOUT 126

typedef short bf16x8 __attribute__((ext_vector_type(8)));   // 4 VGPR
typedef float f32x4 __attribute__((ext_vector_type(4)));
typedef float f4v __attribute__((ext_vector_type(4)));
typedef unsigned int u32;
typedef u32 u32x4 __attribute__((ext_vector_type(4)));

#define MFMA(a, b, c) __builtin_amdgcn_mfma_f32_16x16x32_bf16((a), (b), (c), 0, 0, 0)
// (a>>16) | (c & 0xffff0000) == v_perm_b32(hi=c, lo=a, 0x07060302)
#define PKHI(a, c) __builtin_amdgcn_perm((c), (a), 0x07060302u)

// ROUND 25: row-triple k-slot bijection -> 3 VMEM instr/plane (was 8).
// r22 evidence: wall = ~11.7 cyc per scattered VMEM INSTRUCTION (line-touch
// cuts moved almost nothing); r23/r24 LDS staging passed but cost more than
// the gathers (32.2 vs 29.6 us). So cut instruction count directly: group g
// owns rows 2g and 2g+1 (row=(c,kh)=(r/3,r%3)); slots j=0-2 = (row 2g,
// kw=j), j=3-5 = (row 2g+1, kw=j-3), j=6 = (row 8, kw=g) for g<3, j=7 pad.
// A lane's 3 taps of a row are CONSECUTIVE cols q15..q15+2 -> one unaligned
// dwordx4 per row (4B align, HW-supported) + one dword for row 8:
// 3 loads/plane. Pack stays 4 perms: d0=pk(a0,a1), d1=pk(a2,b0),
// d2=pk(b1,b2), d3=pk(c,c) (slot 7 pad, A-side weight 0). The x4's unused
// 4th element stays in-bounds (wraps within a plane; row 8 - the only row
// reaching the tensor end - is the capped dword). Numerics (x trunc-bf16,
// w RTN-bf16, 3 MFMA/step) and the r20-22 distance-2 pack-then-reload
// register schedule are unchanged -> absmax must stay 3.906e-3.
struct Raw {
  f4v a;   // row 2g, cols q15..q15+3
  f4v b;   // row 2g+1
  u32 c;   // row 8 (g<3) / dummy (g=3)
};

__device__ __forceinline__ f4v ld4(const float* p) {
  f4v v;
  __builtin_memcpy(&v, p, 16);  // align-4 vector load (gfx950 unaligned OK)
  return v;
}

__device__ __forceinline__ void load_raw(const float* __restrict__ xp,
                                         int offA, int offB, int offC,
                                         Raw& r) {
  r.a = ld4(xp + offA);
  r.b = ld4(xp + offB);
  r.c = __float_as_uint(xp[offC]);
}

__device__ __forceinline__ void pack_hi(const Raw& r, bf16x8& fh) {
  u32x4 hd;
  hd[0] = PKHI(__float_as_uint(r.a.x), __float_as_uint(r.a.y));
  hd[1] = PKHI(__float_as_uint(r.a.z), __float_as_uint(r.b.x));
  hd[2] = PKHI(__float_as_uint(r.b.y), __float_as_uint(r.b.z));
  hd[3] = PKHI(r.c, r.c);
  fh = __builtin_bit_cast(bf16x8, hd);
}

// One dz step (r20-r22 distance-2 schedule): pack plane dz+2 from ubuf,
// reload the SAME buffer with plane dz+4 (anti-dependency keeps order),
// 3 MFMAs (K = 3 planes x 27), running min.
__device__ __forceinline__ void dz_step(const float* __restrict__ xb, int pnext,
                                        int offA, int offB, int offC,
                                        const bf16x8 (&wa)[3], Raw& ubuf,
                                        bf16x8& fa, bf16x8& fb, bf16x8& fc,
                                        const f32x4& z4, f32x4& mn) {
  pack_hi(ubuf, fc);                                     // consume dz+2
  load_raw(xb + (size_t)pnext * HW, offA, offB, offC, ubuf);  // prefetch dz+4
  f32x4 acc = MFMA(wa[0], fa, z4);
  acc = MFMA(wa[1], fb, acc);
  acc = MFMA(wa[2], fc, acc);
  mn.x = fminf(mn.x, acc.x);
  mn.y = fminf(mn.y, acc.y);
  mn.z = fminf(mn.z, acc.z);
  mn.w = fminf(mn.w, acc.w);
}

// Tail variant: no prefetch.
__device__ __forceinline__ void dz_step_nl(const bf16x8 (&wa)[3], Raw& ubuf,
                                           bf16x8& fa, bf16x8& fb, bf16x8& fc,
                                           const f32x4& z4, f32x4& mn) {
  pack_hi(ubuf, fc);
  f32x4 acc = MFMA(wa[0], fa, z4);
  acc = MFMA(wa[1], fb, acc);
  acc = MFMA(wa[2], fc, acc);
  mn.x = fminf(mn.x, acc.x);
  mn.y = fminf(mn.y, acc.y);
  mn.z = fminf(mn.z, acc.z);
  mn.w = fminf(mn.w, acc.w);
}

// 256-thread blocks = 4 independent waves, wave wv handles w-tile
// wti = blockIdx.z*4+wv. Implicit-GEMM per wave: C[oc=16][px=16] via
// mfma_f32_16x16x32_bf16, A = weights (oc x K, single-term RTN-bf16),
// B = im2col (K x px, single-term trunc-bf16). A and B share the row-triple
// bijection above, so the contraction is a k-order permutation only.
// C/D: col=lane&15=pixel, row=(lane>>4)*4+reg=oc (m89-verified).
__global__ __launch_bounds__(256) void conv_min_softmax_mfma(
    const float* __restrict__ x, const float* __restrict__ wt,
    float* __restrict__ out) {
  const int tid = threadIdx.x;
  const int lane = tid & 63;
  const int wv = tid >> 6;            // wave id 0..3
  const int q15 = lane & 15;          // pixel (B col) and oc (A row)
  const int g = lane >> 4;            // row-pair group
  const int b = blockIdx.x;
  const int h = blockIdx.y;
  const int wti = blockIdx.z * 4 + wv;
  const int w0 = (wti == 7) ? 110 : wti * 16;  // overlap last tile (no OOB)

  // Per-lane plane-relative offsets for the 3 loads.
  const int rA = 2 * g;        // rows 0,2,4,6
  const int rB = 2 * g + 1;    // rows 1,3,5,7
  const int base = w0 + q15;
  const int offA = (rA / 3) * DD * HW + (rA % 3) * WW + base;
  const int offB = (rB / 3) * DD * HW + (rB % 3) * WW + base;
  const int offC = 2 * DD * HW + 2 * WW + base + ((g < 3) ? g : 0);

  // Weight fragments (A), per kd-tile t: single-term RTN bf16, same
  // row-triple bijection; pads (j=7 always; j=6 for g=3) = 0.
  bf16x8 wa[3];
#pragma unroll
  for (int t = 0; t < 3; ++t) {
    u32 u[8];
#pragma unroll
    for (int j = 0; j < 8; ++j) {
      float v = 0.f;
      if (j < 3) {
        v = wt[q15 * 81 + (rA / 3) * 27 + t * 9 + (rA % 3) * 3 + j];
      } else if (j < 6) {
        v = wt[q15 * 81 + (rB / 3) * 27 + t * 9 + (rB % 3) * 3 + (j - 3)];
      } else if (j == 6 && g < 3) {
        v = wt[q15 * 81 + 2 * 27 + t * 9 + 2 * 3 + g];
      }
      const u32 ub = __float_as_uint(v);
      u[j] = ub + 0x7fffu + ((ub >> 16) & 1u);  // round-to-nearest-even bf16
    }
    u32x4 hd;
#pragma unroll
    for (int p = 0; p < 4; ++p) hd[p] = PKHI(u[2 * p], u[2 * p + 1]);
    wa[t] = __builtin_bit_cast(bf16x8, hd);
  }

  const float* xb = x + ((size_t)b * CC * DD) * HW + (size_t)h * WW;

  // Prologue: planes 0,1 packed immediately; planes 2,3 raw in U0,U1.
  Raw u0, u1;
  bf16x8 f0, f1, f2;
  load_raw(xb + (size_t)0 * HW, offA, offB, offC, u0);
  load_raw(xb + (size_t)1 * HW, offA, offB, offC, u1);
  pack_hi(u0, f0);
  pack_hi(u1, f1);
  load_raw(xb + (size_t)2 * HW, offA, offB, offC, u0);
  load_raw(xb + (size_t)3 * HW, offA, offB, offC, u1);

  const f32x4 z4 = {0.f, 0.f, 0.f, 0.f};
  f32x4 mn = {INFINITY, INFINITY, INFINITY, INFINITY};

  // dz = 0..17: period-6 (U parity x F rotation); step dz packs plane dz+2
  // and prefetches plane dz+4.
#pragma clang loop unroll(disable)
  for (int dzb = 0; dzb < 18; dzb += 6) {
    dz_step(xb, dzb + 4, offA, offB, offC, wa, u0, f0, f1, f2, z4, mn);
    dz_step(xb, dzb + 5, offA, offB, offC, wa, u1, f1, f2, f0, z4, mn);
    dz_step(xb, dzb + 6, offA, offB, offC, wa, u0, f2, f0, f1, z4, mn);
    dz_step(xb, dzb + 7, offA, offB, offC, wa, u1, f0, f1, f2, z4, mn);
    dz_step(xb, dzb + 8, offA, offB, offC, wa, u0, f1, f2, f0, z4, mn);
    dz_step(xb, dzb + 9, offA, offB, offC, wa, u1, f2, f0, f1, z4, mn);
  }
  // Tail dz = 18..21; last two steps have no remaining planes to prefetch.
  dz_step(xb, 22, offA, offB, offC, wa, u0, f0, f1, f2, z4, mn);
  dz_step(xb, 23, offA, offB, offC, wa, u1, f1, f2, f0, z4, mn);
  dz_step_nl(wa, u0, f2, f0, f1, z4, mn);
  dz_step_nl(wa, u1, f0, f1, f2, z4, mn);

  // Softmax over oc for this lane's pixel: 4 in-lane regs (oc = g*4+r) +
  // lanes sharing q15 across g (xor 16, 32).
  float mx = fmaxf(fmaxf(mn.x, mn.y), fmaxf(mn.z, mn.w));
  mx = fmaxf(mx, __shfl_xor(mx, 16));
  mx = fmaxf(mx, __shfl_xor(mx, 32));
  const float e0 = __expf(mn.x - mx);
  const float e1 = __expf(mn.y - mx);
  const float e2 = __expf(mn.z - mx);
  const float e3 = __expf(mn.w - mx);
  float s = (e0 + e1) + (e2 + e3);
  s += __shfl_xor(s, 16);
  s += __shfl_xor(s, 32);
  const float inv = 1.f / s;

  // Store: out[b][oc = g*4+r][h][w0+q15]; 16 consecutive pixels per (g,r).
  float* ob = out + (((size_t)(b * OCC + g * 4) * HOUT + h) * WOUT) + w0 + q15;
  const size_t os = (size_t)HOUT * WOUT;
  ob[0 * os] = e0 * inv;
  ob[1 * os] = e1 * inv;
  ob[2 * os] = e2 * inv;
  ob[3 * os] = e3 * inv;
}

extern "C" void kernel_launch(void* const* d_in, const int* in_sizes, int n_in,
                              void* d_out, int out_size, void* d_ws, size_t ws_size,
                              hipStream_t stream) {
  const float* x = (const float*)d_in[0];
  const float* wt = (const float*)d_in[1];
  float* out = (float*)d_out;

  dim3 grid(BB, HOUT, 2);   // b (XCD-pinned), h, w-tile-pair
  dim3 block(256, 1, 1);    // 4 waves = 4 w-tiles
  conv_min_softmax_mfma<<<grid, block, 0, stream>>>(x, wt, out);
}